// Round 2
// baseline (1971.698 us; speedup 1.0000x reference)
//
#include <hip/hip_runtime.h>
#include <math.h>

// All reference tensors are float32 -> inputs are const float*, output float*.

// Problem constants
constexpr int Bn = 4;          // batch

// ---- workspace layout (float offsets) ----
constexpr size_t OFF_CUR  = 0;                        // 4*16384*64
constexpr size_t OFF_DC   = OFF_CUR + 4194304;        // 4*16384*64
constexpr size_t OFF_T0   = OFF_DC  + 4194304;        // fuse outputs per level
constexpr size_t OFF_T1   = OFF_T0  + 4194304;
constexpr size_t OFF_T2   = OFF_T1  + 1048576;
constexpr size_t OFF_T3   = OFF_T2  + 262144;
constexpr size_t OFF_DCWT = OFF_T3  + 65536;          // 4*576*64  transposed deform weights
constexpr size_t OFF_OFWT = OFF_DCWT + 147456;        // 4*576*18  transposed offset-conv weights
constexpr size_t OFF_WSUM = OFF_OFWT + 41472;         // 4*64*64   cumulative fuse weights [l][c][o]
constexpr size_t OFF_SUMS = OFF_WSUM + 16384;         // 4*64*256  slotted SE partial sums
constexpr size_t OFF_G    = OFF_SUMS + 65536;         // 4*4*64    SE gates
// total = 14,231,040 floats = ~57 MB

// ---- prep: transpose weights, build cumulative fuse weights, zero SE sums ----
__global__ void prep_k(const float* __restrict__ dc_w, const float* __restrict__ off_w,
                       const float* __restrict__ fuse_w, float* __restrict__ ws){
  int i = blockIdx.x * 256 + threadIdx.x;
  if (i < 147456){
    int l = i / 36864, r = i % 36864, j = r / 64, o = r % 64, c = j / 9, k = j % 9;
    ws[OFF_DCWT + i] = dc_w[((l*64 + o)*64 + c)*9 + k];
  } else if (i < 147456 + 41472){
    int t = i - 147456;
    int l = t / 10368, r = t % 10368, j = r / 18, m = r % 18, c = j / 9, k = j % 9;
    ws[OFF_OFWT + t] = off_w[((l*18 + m)*64 + c)*9 + k];
  } else if (i < 147456 + 41472 + 16384){
    int t = i - (147456 + 41472);
    int l = t / 4096, r = t % 4096, c = r / 64, o = r % 64;
    float s = 0.f;
    for (int jl = 0; jl <= l; jl++) s += fuse_w[o*256 + jl*64 + c];
    ws[OFF_WSUM + t] = s;
  } else if (i < 147456 + 41472 + 16384 + 65536){
    ws[OFF_SUMS + (i - (147456 + 41472 + 16384))] = 0.f;
  }
}

// ---- convert x: NCHW -> NHWC ----
__global__ void cvt_k(const float* __restrict__ x, float* __restrict__ cur){
  int i = blockIdx.x * 256 + threadIdx.x;       // exactly 4*16384*64 threads
  int c = i & 63, bp = i >> 6, b = bp >> 14, p = bp & 16383;
  cur[i] = x[((b << 6) + c) * 16384 + p];
}

// ---- downsample-by-2 (== 2x2 avg pool) with SE gate of previous level ----
template<int H>
__global__ void down_k(const float* __restrict__ dcin, const float* __restrict__ g,
                       float* __restrict__ cur, int lprev){
  constexpr int W = H, P = H * W;
  int i = blockIdx.x * 256 + threadIdx.x;
  if (i >= Bn * P * 64) return;
  int c = i & 63, bp = i >> 6, b = bp / P, p = bp % P, h = p / W, w = p % W;
  const int W2 = 2 * W;
  const float* s = dcin + (size_t)b * 4 * P * 64;
  size_t o00 = ((size_t)(2*h) * W2 + 2*w) * 64 + c;
  float v = 0.25f * (s[o00] + s[o00 + 64] + s[o00 + (size_t)W2*64] + s[o00 + (size_t)W2*64 + 64]);
  cur[i] = v * g[lprev * 256 + (b << 6) + c];
}

// ---- fused: offset conv3x3 + bilinear deform sampling + 576x64 matmul + SE colsum ----
// one wave per block, 8 pixels per block
template<int H, int LVL>
__global__ __launch_bounds__(64) void deform_k(
    const float* __restrict__ cur, const float* __restrict__ ws_all,
    const float* __restrict__ off_bias, const float* __restrict__ dc_bias,
    float* __restrict__ dc, float* __restrict__ sums){
  constexpr int W = H, P = H * W;
  __shared__ float patch[8 * 576];   // [p][c*9+k]; reused as sampled vals
  __shared__ float offs[8 * 18];
  const float* owt = ws_all + OFF_OFWT + LVL * 576 * 18;
  const float* wt  = ws_all + OFF_DCWT + (size_t)LVL * 576 * 64;
  int lane = threadIdx.x;
  int pix0 = blockIdx.x * 8;
  int b = pix0 / P, pb = pix0 % P;
  const float* curb = cur + (size_t)b * P * 64;

  // A: stage zero-padded 3x3 patches (lane = channel)
  for (int p = 0; p < 8; p++){
    int pp = pb + p, h = pp / W, w = pp % W;
    #pragma unroll
    for (int k = 0; k < 9; k++){
      int yy = h + k/3 - 1, xx = w + k%3 - 1;
      float v = 0.f;
      if (yy >= 0 && yy < H && xx >= 0 && xx < W) v = curb[((size_t)yy*W + xx)*64 + lane];
      patch[p*576 + lane*9 + k] = v;
    }
  }
  __syncthreads();

  // B: offset conv — 18 outputs x 3 lane-parts
  if (lane < 54){
    int m = lane / 3, part = lane % 3;
    float ob = off_bias[LVL*18 + m];
    for (int p = 0; p < 8; p++){
      float a = 0.f;
      for (int j = part; j < 576; j += 3) a += patch[p*576 + j] * owt[j*18 + m];
      float a1 = __shfl_down(a, 1);
      float a2 = __shfl_down(a, 2);
      if (part == 0) offs[p*18 + m] = a + a1 + a2 + ob;
    }
  }
  __syncthreads();

  // C: bilinear sampling at offset taps (lane = channel); overwrite patch with vals
  for (int p = 0; p < 8; p++){
    int pp = pb + p, h = pp / W, w = pp % W;
    #pragma unroll
    for (int k = 0; k < 9; k++){
      float py = (float)(h + k/3 - 1) + offs[p*18 + 2*k];
      float px = (float)(w + k%3 - 1) + offs[p*18 + 2*k + 1];
      float y0f = floorf(py), x0f = floorf(px);
      float fy = py - y0f, fx = px - x0f;
      int y0 = (int)y0f, x0 = (int)x0f;
      int y1 = y0 + 1, x1 = x0 + 1;
      float v = 0.f;
      bool vy0 = (y0 >= 0) & (y0 < H), vy1 = (y1 >= 0) & (y1 < H);
      bool vx0 = (x0 >= 0) & (x0 < W), vx1 = (x1 >= 0) & (x1 < W);
      if (vy0 & vx0) v += (1.f-fy)*(1.f-fx) * curb[((size_t)y0*W + x0)*64 + lane];
      if (vy0 & vx1) v += (1.f-fy)*fx       * curb[((size_t)y0*W + x1)*64 + lane];
      if (vy1 & vx0) v += fy*(1.f-fx)       * curb[((size_t)y1*W + x0)*64 + lane];
      if (vy1 & vx1) v += fy*fx             * curb[((size_t)y1*W + x1)*64 + lane];
      patch[p*576 + lane*9 + k] = v;
    }
  }
  __syncthreads();

  // D: 576 x 64 matmul (lane = output channel), 8 pixels per pass
  float bias = dc_bias[LVL*64 + lane];
  float acc[8];
  #pragma unroll
  for (int p = 0; p < 8; p++) acc[p] = bias;
  for (int j = 0; j < 576; j += 4){
    float w0 = wt[(j+0)*64 + lane], w1 = wt[(j+1)*64 + lane];
    float w2 = wt[(j+2)*64 + lane], w3 = wt[(j+3)*64 + lane];
    #pragma unroll
    for (int p = 0; p < 8; p++){
      const float4 v = *(const float4*)&patch[p*576 + j];
      acc[p] += v.x*w0 + v.y*w1 + v.z*w2 + v.w*w3;
    }
  }
  float ssum = 0.f;
  float* dcb = dc + ((size_t)b*P + pb) * 64;
  #pragma unroll
  for (int p = 0; p < 8; p++){ dcb[p*64 + lane] = acc[p]; ssum += acc[p]; }
  int slot = blockIdx.x & 63;
  atomicAdd(&sums[(LVL*64 + slot)*256 + (b << 6) + lane], ssum);
}

// ---- SE: reduce slotted sums -> mean -> fc-relu-fc-sigmoid -> gates ----
__global__ void se_k(const float* __restrict__ sums, const float* __restrict__ w1p,
                     const float* __restrict__ b1p, const float* __restrict__ w2p,
                     const float* __restrict__ b2p, float* __restrict__ g, int l, int P){
  __shared__ float m_s[256];
  __shared__ float h_s[16];
  int t = threadIdx.x;
  float s = 0.f;
  for (int slot = 0; slot < 64; slot++) s += sums[(l*64 + slot)*256 + t];
  m_s[t] = s / (float)P;
  __syncthreads();
  if (t < 16){
    int b = t >> 2, r = t & 3;
    float a = b1p[l*4 + r];
    for (int c = 0; c < 64; c++) a += m_s[b*64 + c] * w1p[(l*4 + r)*64 + c];
    h_s[t] = fmaxf(a, 0.f);
  }
  __syncthreads();
  int b = t >> 6, c = t & 63;
  float a = b2p[l*64 + c];
  for (int r = 0; r < 4; r++) a += h_s[b*4 + r] * w2p[(l*64 + c)*4 + r];
  g[l*256 + t] = 1.f / (1.f + expf(-a));
}

// ---- fuse: per-pixel (dc * gate) @ Wsum_l -> tmp_l (level res) ----
__global__ __launch_bounds__(64) void fuse_k(const float* __restrict__ dcv, const float* __restrict__ g,
                                             const float* __restrict__ ws_all, float* __restrict__ tmp,
                                             int l, int P){
  __shared__ float inv[8 * 64];
  int lane = threadIdx.x;
  int pix0 = blockIdx.x * 8;
  int b = pix0 / P;
  const float* wsl = ws_all + OFF_WSUM + (size_t)l * 4096;
  float gl = g[l*256 + (b << 6) + lane];
  #pragma unroll
  for (int p = 0; p < 8; p++) inv[p*64 + lane] = dcv[(size_t)(pix0 + p)*64 + lane] * gl;
  __syncthreads();
  float acc[8];
  #pragma unroll
  for (int p = 0; p < 8; p++) acc[p] = 0.f;
  for (int c = 0; c < 64; c += 4){
    float w0 = wsl[(c+0)*64 + lane], w1 = wsl[(c+1)*64 + lane];
    float w2 = wsl[(c+2)*64 + lane], w3 = wsl[(c+3)*64 + lane];
    #pragma unroll
    for (int p = 0; p < 8; p++){
      const float4 v = *(const float4*)&inv[p*64 + c];
      acc[p] += v.x*w0 + v.y*w1 + v.z*w2 + v.w*w3;
    }
  }
  #pragma unroll
  for (int p = 0; p < 8; p++) tmp[(size_t)(pix0 + p)*64 + lane] = acc[p];
}

// ---- final: 4x bilinear upsample + sum + fuse bias -> f32 NCHW ----
__global__ void final_k(const float* __restrict__ ws_all, const float* __restrict__ fuse_bias,
                        float* __restrict__ out){
  int i = blockIdx.x * 256 + threadIdx.x;     // exactly 4*64*16384
  int w = i & 127, h = (i >> 7) & 127, o = (i >> 14) & 63, b = i >> 20;
  float acc = fuse_bias[o];
  const float* tarr[4] = {ws_all + OFF_T0, ws_all + OFF_T1, ws_all + OFF_T2, ws_all + OFF_T3};
  #pragma unroll
  for (int l = 0; l < 4; l++){
    int Hl = 128 >> l;
    float scale = 1.0f / (float)(1 << l);
    float sy = fminf(fmaxf((h + 0.5f)*scale - 0.5f, 0.f), (float)(Hl - 1));
    float sx = fminf(fmaxf((w + 0.5f)*scale - 0.5f, 0.f), (float)(Hl - 1));
    int y0 = (int)sy, x0 = (int)sx;           // sy,sx >= 0 -> trunc == floor
    float fy = sy - y0, fx = sx - x0;
    int y1 = min(y0 + 1, Hl - 1), x1 = min(x0 + 1, Hl - 1);
    const float* tb = tarr[l] + ((size_t)b * Hl * Hl) * 64;
    float v00 = tb[((size_t)y0*Hl + x0)*64 + o], v01 = tb[((size_t)y0*Hl + x1)*64 + o];
    float v10 = tb[((size_t)y1*Hl + x0)*64 + o], v11 = tb[((size_t)y1*Hl + x1)*64 + o];
    acc += (1.f-fy)*((1.f-fx)*v00 + fx*v01) + fy*((1.f-fx)*v10 + fx*v11);
  }
  out[i] = acc;
}

extern "C" void kernel_launch(void* const* d_in, const int* in_sizes, int n_in,
                              void* d_out, int out_size, void* d_ws, size_t ws_size,
                              hipStream_t stream){
  (void)in_sizes; (void)n_in; (void)out_size; (void)ws_size;
  const float* x      = (const float*)d_in[0];
  const float* off_w  = (const float*)d_in[1];
  const float* off_b  = (const float*)d_in[2];
  const float* dc_w   = (const float*)d_in[3];
  const float* dc_b   = (const float*)d_in[4];
  const float* se_w1  = (const float*)d_in[5];
  const float* se_b1  = (const float*)d_in[6];
  const float* se_w2  = (const float*)d_in[7];
  const float* se_b2  = (const float*)d_in[8];
  const float* fuse_w = (const float*)d_in[9];
  const float* fuse_b = (const float*)d_in[10];
  float* out = (float*)d_out;
  float* ws = (float*)d_ws;
  float* cur  = ws + OFF_CUR;
  float* dc   = ws + OFF_DC;
  float* tmp[4] = {ws + OFF_T0, ws + OFF_T1, ws + OFF_T2, ws + OFF_T3};
  float* sums = ws + OFF_SUMS;
  float* g    = ws + OFF_G;

  prep_k<<<(270848 + 255)/256, 256, 0, stream>>>(dc_w, off_w, fuse_w, ws);
  cvt_k<<<16384, 256, 0, stream>>>(x, cur);

  for (int l = 0; l < 4; l++){
    int H = 128 >> l, P = H * H;
    if (l > 0){
      int N = Bn * P * 64;
      int nb = (N + 255) / 256;
      if      (H == 64) down_k<64><<<nb, 256, 0, stream>>>(dc, g, cur, l - 1);
      else if (H == 32) down_k<32><<<nb, 256, 0, stream>>>(dc, g, cur, l - 1);
      else              down_k<16><<<nb, 256, 0, stream>>>(dc, g, cur, l - 1);
    }
    int nb = Bn * P / 8;
    switch (l){
      case 0: deform_k<128,0><<<nb, 64, 0, stream>>>(cur, ws, off_b, dc_b, dc, sums); break;
      case 1: deform_k< 64,1><<<nb, 64, 0, stream>>>(cur, ws, off_b, dc_b, dc, sums); break;
      case 2: deform_k< 32,2><<<nb, 64, 0, stream>>>(cur, ws, off_b, dc_b, dc, sums); break;
      case 3: deform_k< 16,3><<<nb, 64, 0, stream>>>(cur, ws, off_b, dc_b, dc, sums); break;
    }
    se_k<<<1, 256, 0, stream>>>(sums, se_w1, se_b1, se_w2, se_b2, g, l, P);
    fuse_k<<<nb, 64, 0, stream>>>(dc, g, ws, tmp[l], l, P);
  }
  final_k<<<16384, 256, 0, stream>>>(ws, fuse_b, out);
}

// Round 3
// 776.329 us; speedup vs baseline: 2.5398x; 2.5398x over previous
//
#include <hip/hip_runtime.h>
#include <math.h>

// All reference tensors are float32 -> inputs are const float*, output float*.

constexpr int Bn = 4;          // batch

typedef __attribute__((ext_vector_type(8))) short short8;   // 8 bf16 (4 VGPRs)
typedef __attribute__((ext_vector_type(4))) float f32x4;    // MFMA 16x16 acc

static __device__ __forceinline__ short f2b(float f){
  union { float f; unsigned u; } v; v.f = f;
  unsigned r = v.u + 0x7fffu + ((v.u >> 16) & 1u);   // RNE
  return (short)(r >> 16);
}

// ---- workspace layout (float offsets; all multiples of 4 -> 16B aligned) ----
constexpr size_t OFF_CUR   = 0;                         // 4*16384*64 f32 NHWC
constexpr size_t OFF_DC    = OFF_CUR  + 4194304;        // 4*16384*64
constexpr size_t OFF_T0    = OFF_DC   + 4194304;
constexpr size_t OFF_T1    = OFF_T0   + 4194304;
constexpr size_t OFF_T2    = OFF_T1   + 1048576;
constexpr size_t OFF_T3    = OFF_T2   + 262144;
constexpr size_t OFF_WSUMT = OFF_T3   + 65536;          // bf16 [4][64][64]   (8192 f)
constexpr size_t OFF_DCWT  = OFF_WSUMT + 8192;          // bf16 [4][64][576]  (73728 f)
constexpr size_t OFF_OWT   = OFF_DCWT  + 73728;         // bf16 [4][32][576]  (36864 f)
constexpr size_t OFF_SUMS  = OFF_OWT   + 36864;         // f32 [4][64 slots][256]
constexpr size_t OFF_G     = OFF_SUMS  + 65536;         // f32 [4][4][64]
// total = 14,144,512 floats ~= 56.6 MB

// ---- prep: convert weights to bf16 (N-major, K-contiguous), cumulative fuse, zero SE sums ----
__global__ void prep_k(const float* __restrict__ dc_w, const float* __restrict__ off_w,
                       const float* __restrict__ fuse_w, float* __restrict__ ws){
  int i = blockIdx.x * 256 + threadIdx.x;
  short* dcwT  = (short*)(ws + OFF_DCWT);
  short* owT   = (short*)(ws + OFF_OWT);
  short* wsumT = (short*)(ws + OFF_WSUMT);
  if (i < 147456){
    dcwT[i] = f2b(dc_w[i]);                       // [l][o][c*9+kt] == flat order
  } else if (i < 147456 + 73728){
    int t = i - 147456;
    int l = t / 18432, r = t % 18432, m = r / 576, k = r % 576;
    owT[t] = (m < 18) ? f2b(off_w[(l*18 + m)*576 + k]) : (short)0;
  } else if (i < 147456 + 73728 + 16384){
    int t = i - (147456 + 73728);
    int l = t / 4096, r = t % 4096, o = r / 64, c = r % 64;
    float s = 0.f;
    for (int jl = 0; jl <= l; jl++) s += fuse_w[o*256 + jl*64 + c];
    wsumT[t] = f2b(s);
  } else if (i < 147456 + 73728 + 16384 + 65536){
    ws[OFF_SUMS + (i - (147456 + 73728 + 16384))] = 0.f;
  }
}

// ---- convert x: NCHW -> NHWC ----
__global__ void cvt_k(const float* __restrict__ x, float* __restrict__ cur){
  int i = blockIdx.x * 256 + threadIdx.x;
  int c = i & 63, bp = i >> 6, b = bp >> 14, p = bp & 16383;
  cur[i] = x[((b << 6) + c) * 16384 + p];
}

// ---- downsample-by-2 (== 2x2 avg pool) with SE gate of previous level ----
template<int H>
__global__ void down_k(const float* __restrict__ dcin, const float* __restrict__ g,
                       float* __restrict__ cur, int lprev){
  constexpr int W = H, P = H * W;
  int i = blockIdx.x * 256 + threadIdx.x;
  if (i >= Bn * P * 64) return;
  int c = i & 63, bp = i >> 6, b = bp / P, p = bp % P, h = p / W, w = p % W;
  const int W2 = 2 * W;
  const float* s = dcin + (size_t)b * 4 * P * 64;
  size_t o00 = ((size_t)(2*h) * W2 + 2*w) * 64 + c;
  float v = 0.25f * (s[o00] + s[o00 + 64] + s[o00 + (size_t)W2*64] + s[o00 + (size_t)W2*64 + 64]);
  cur[i] = v * g[lprev * 256 + (b << 6) + c];
}

// ---- fused: offset conv (MFMA) + bilinear sampling + deform GEMM (MFMA) + SE colsum ----
// one wave per block, 16 pixels per block
template<int H, int LVL>
__global__ __launch_bounds__(64) void deform_k(
    const float* __restrict__ cur, const float* __restrict__ ws_all,
    const float* __restrict__ off_bias, const float* __restrict__ dc_bias,
    float* __restrict__ dc, float* __restrict__ sums){
  constexpr int W = H, P = H * W;
  __shared__ __align__(16) short valA[16][584];   // bf16, pad 576->584 (2-way banks)
  __shared__ float offs[16][18];
  const short* owt = (const short*)(ws_all + OFF_OWT) + LVL * 32 * 576;
  const short* dcw = (const short*)(ws_all + OFF_DCWT) + (size_t)LVL * 64 * 576;
  const int lane = threadIdx.x;
  const int c0 = lane & 15, quad = lane >> 4, q4 = quad * 4;
  const int pix0 = blockIdx.x * 16;
  const int b = pix0 / P, pb = pix0 % P;
  const float* curb = cur + (size_t)b * P * 64;

  // A: stage zero-padded 3x3 patches, bf16 (lane = channel)
  for (int p = 0; p < 16; p++){
    int pp = pb + p, h = pp / W, w = pp % W;
    #pragma unroll
    for (int k = 0; k < 9; k++){
      int yy = h + k/3 - 1, xx = w + k%3 - 1;
      float v = 0.f;
      if (yy >= 0 && yy < H && xx >= 0 && xx < W) v = curb[((size_t)yy*W + xx)*64 + lane];
      valA[p][lane*9 + k] = f2b(v);
    }
  }
  __syncthreads();

  // B: offset conv via MFMA  [16 x 576] @ [576 x 32(pad of 18)]
  {
    f32x4 oacc[2] = {{0,0,0,0},{0,0,0,0}};
    for (int ch = 0; ch < 18; ch++){
      short8 a = *(const short8*)&valA[c0][ch*32 + quad*8];
      #pragma unroll
      for (int t = 0; t < 2; t++){
        short8 bf = *(const short8*)&owt[(t*16 + c0)*576 + ch*32 + quad*8];
        oacc[t] = __builtin_amdgcn_mfma_f32_16x16x32_bf16(a, bf, oacc[t], 0, 0, 0);
      }
    }
    #pragma unroll
    for (int t = 0; t < 2; t++){
      int comp = t*16 + c0;
      if (comp < 18){
        float ob = off_bias[LVL*18 + comp];
        #pragma unroll
        for (int r = 0; r < 4; r++) offs[q4 + r][comp] = oacc[t][r] + ob;
      }
    }
  }
  __syncthreads();

  // C: bilinear sampling at offset taps (lane = channel); overwrite valA
  for (int p = 0; p < 16; p++){
    int pp = pb + p, h = pp / W, w = pp % W;
    #pragma unroll
    for (int k = 0; k < 9; k++){
      float py = (float)(h + k/3 - 1) + offs[p][2*k];
      float px = (float)(w + k%3 - 1) + offs[p][2*k + 1];
      float y0f = floorf(py), x0f = floorf(px);
      float fy = py - y0f, fx = px - x0f;
      int y0 = (int)y0f, x0 = (int)x0f;
      int y1 = y0 + 1, x1 = x0 + 1;
      float v = 0.f;
      bool vy0 = (y0 >= 0) & (y0 < H), vy1 = (y1 >= 0) & (y1 < H);
      bool vx0 = (x0 >= 0) & (x0 < W), vx1 = (x1 >= 0) & (x1 < W);
      if (vy0 & vx0) v += (1.f-fy)*(1.f-fx) * curb[((size_t)y0*W + x0)*64 + lane];
      if (vy0 & vx1) v += (1.f-fy)*fx       * curb[((size_t)y0*W + x1)*64 + lane];
      if (vy1 & vx0) v += fy*(1.f-fx)       * curb[((size_t)y1*W + x0)*64 + lane];
      if (vy1 & vx1) v += fy*fx             * curb[((size_t)y1*W + x1)*64 + lane];
      valA[p][lane*9 + k] = f2b(v);
    }
  }
  __syncthreads();

  // D: deform GEMM via MFMA  [16 x 576] @ [576 x 64], bias in acc
  f32x4 acc[4];
  #pragma unroll
  for (int t = 0; t < 4; t++){
    float bt = dc_bias[LVL*64 + t*16 + c0];
    acc[t] = (f32x4){bt, bt, bt, bt};
  }
  for (int ch = 0; ch < 18; ch++){
    short8 a = *(const short8*)&valA[c0][ch*32 + quad*8];
    #pragma unroll
    for (int t = 0; t < 4; t++){
      short8 bf = *(const short8*)&dcw[(t*16 + c0)*576 + ch*32 + quad*8];
      acc[t] = __builtin_amdgcn_mfma_f32_16x16x32_bf16(a, bf, acc[t], 0, 0, 0);
    }
  }

  // epilogue: store dc (NHWC) + SE column sums
  int slot = blockIdx.x & 63;
  #pragma unroll
  for (int t = 0; t < 4; t++){
    int n = t*16 + c0;
    #pragma unroll
    for (int r = 0; r < 4; r++)
      dc[(size_t)(pix0 + q4 + r)*64 + n] = acc[t][r];
    float s = acc[t][0] + acc[t][1] + acc[t][2] + acc[t][3];
    s += __shfl_xor(s, 16);
    s += __shfl_xor(s, 32);
    if (quad == 0) atomicAdd(&sums[(LVL*64 + slot)*256 + (b << 6) + n], s);
  }
}

// ---- SE: reduce slotted sums -> mean -> fc-relu-fc-sigmoid -> gates ----
__global__ void se_k(const float* __restrict__ sums, const float* __restrict__ w1p,
                     const float* __restrict__ b1p, const float* __restrict__ w2p,
                     const float* __restrict__ b2p, float* __restrict__ g, int l, int P){
  __shared__ float m_s[256];
  __shared__ float h_s[16];
  int t = threadIdx.x;
  float s = 0.f;
  for (int slot = 0; slot < 64; slot++) s += sums[(l*64 + slot)*256 + t];
  m_s[t] = s / (float)P;
  __syncthreads();
  if (t < 16){
    int b = t >> 2, r = t & 3;
    float a = b1p[l*4 + r];
    for (int c = 0; c < 64; c++) a += m_s[b*64 + c] * w1p[(l*4 + r)*64 + c];
    h_s[t] = fmaxf(a, 0.f);
  }
  __syncthreads();
  int b = t >> 6, c = t & 63;
  float a = b2p[l*64 + c];
  for (int r = 0; r < 4; r++) a += h_s[b*4 + r] * w2p[(l*64 + c)*4 + r];
  g[l*256 + t] = 1.f / (1.f + expf(-a));
}

// ---- fuse: per-pixel (dc * gate) @ Wsum_l via MFMA -> tmp_l (level res) ----
__global__ __launch_bounds__(64) void fuse_k(const float* __restrict__ dcv, const float* __restrict__ g,
                                             const float* __restrict__ ws_all, float* __restrict__ tmp,
                                             int l, int P){
  __shared__ __align__(16) short fA[16][72];      // bf16, pad 64->72
  const short* wsl = (const short*)(ws_all + OFF_WSUMT) + l * 64 * 64;
  const int lane = threadIdx.x;
  const int c0 = lane & 15, quad = lane >> 4, q4 = quad * 4;
  const int pix0 = blockIdx.x * 16;
  const int b = pix0 / P;
  float gl = g[l*256 + (b << 6) + lane];
  for (int p = 0; p < 16; p++)
    fA[p][lane] = f2b(dcv[(size_t)(pix0 + p)*64 + lane] * gl);
  __syncthreads();
  f32x4 acc[4] = {{0,0,0,0},{0,0,0,0},{0,0,0,0},{0,0,0,0}};
  #pragma unroll
  for (int ch = 0; ch < 2; ch++){
    short8 a = *(const short8*)&fA[c0][ch*32 + quad*8];
    #pragma unroll
    for (int t = 0; t < 4; t++){
      short8 bf = *(const short8*)&wsl[(t*16 + c0)*64 + ch*32 + quad*8];
      acc[t] = __builtin_amdgcn_mfma_f32_16x16x32_bf16(a, bf, acc[t], 0, 0, 0);
    }
  }
  #pragma unroll
  for (int t = 0; t < 4; t++)
    #pragma unroll
    for (int r = 0; r < 4; r++)
      tmp[(size_t)(pix0 + q4 + r)*64 + t*16 + c0] = acc[t][r];
}

// ---- final: 4x bilinear upsample + sum + fuse bias -> f32 NCHW ----
__global__ void final_k(const float* __restrict__ ws_all, const float* __restrict__ fuse_bias,
                        float* __restrict__ out){
  int i = blockIdx.x * 256 + threadIdx.x;
  int w = i & 127, h = (i >> 7) & 127, o = (i >> 14) & 63, b = i >> 20;
  float acc = fuse_bias[o];
  const float* tarr[4] = {ws_all + OFF_T0, ws_all + OFF_T1, ws_all + OFF_T2, ws_all + OFF_T3};
  #pragma unroll
  for (int l = 0; l < 4; l++){
    int Hl = 128 >> l;
    float scale = 1.0f / (float)(1 << l);
    float sy = fminf(fmaxf((h + 0.5f)*scale - 0.5f, 0.f), (float)(Hl - 1));
    float sx = fminf(fmaxf((w + 0.5f)*scale - 0.5f, 0.f), (float)(Hl - 1));
    int y0 = (int)sy, x0 = (int)sx;
    float fy = sy - y0, fx = sx - x0;
    int y1 = min(y0 + 1, Hl - 1), x1 = min(x0 + 1, Hl - 1);
    const float* tb = tarr[l] + ((size_t)b * Hl * Hl) * 64;
    float v00 = tb[((size_t)y0*Hl + x0)*64 + o], v01 = tb[((size_t)y0*Hl + x1)*64 + o];
    float v10 = tb[((size_t)y1*Hl + x0)*64 + o], v11 = tb[((size_t)y1*Hl + x1)*64 + o];
    acc += (1.f-fy)*((1.f-fx)*v00 + fx*v01) + fy*((1.f-fx)*v10 + fx*v11);
  }
  out[i] = acc;
}

extern "C" void kernel_launch(void* const* d_in, const int* in_sizes, int n_in,
                              void* d_out, int out_size, void* d_ws, size_t ws_size,
                              hipStream_t stream){
  (void)in_sizes; (void)n_in; (void)out_size; (void)ws_size;
  const float* x      = (const float*)d_in[0];
  const float* off_w  = (const float*)d_in[1];
  const float* off_b  = (const float*)d_in[2];
  const float* dc_w   = (const float*)d_in[3];
  const float* dc_b   = (const float*)d_in[4];
  const float* se_w1  = (const float*)d_in[5];
  const float* se_b1  = (const float*)d_in[6];
  const float* se_w2  = (const float*)d_in[7];
  const float* se_b2  = (const float*)d_in[8];
  const float* fuse_w = (const float*)d_in[9];
  const float* fuse_b = (const float*)d_in[10];
  float* out = (float*)d_out;
  float* ws = (float*)d_ws;
  float* cur  = ws + OFF_CUR;
  float* dc   = ws + OFF_DC;
  float* tmp[4] = {ws + OFF_T0, ws + OFF_T1, ws + OFF_T2, ws + OFF_T3};
  float* sums = ws + OFF_SUMS;
  float* g    = ws + OFF_G;

  prep_k<<<(303104 + 255)/256, 256, 0, stream>>>(dc_w, off_w, fuse_w, ws);
  cvt_k<<<16384, 256, 0, stream>>>(x, cur);

  for (int l = 0; l < 4; l++){
    int H = 128 >> l, P = H * H;
    if (l > 0){
      int N = Bn * P * 64;
      int nb = (N + 255) / 256;
      if      (H == 64) down_k<64><<<nb, 256, 0, stream>>>(dc, g, cur, l - 1);
      else if (H == 32) down_k<32><<<nb, 256, 0, stream>>>(dc, g, cur, l - 1);
      else              down_k<16><<<nb, 256, 0, stream>>>(dc, g, cur, l - 1);
    }
    int nb = Bn * P / 16;
    switch (l){
      case 0: deform_k<128,0><<<nb, 64, 0, stream>>>(cur, ws, off_b, dc_b, dc, sums); break;
      case 1: deform_k< 64,1><<<nb, 64, 0, stream>>>(cur, ws, off_b, dc_b, dc, sums); break;
      case 2: deform_k< 32,2><<<nb, 64, 0, stream>>>(cur, ws, off_b, dc_b, dc, sums); break;
      case 3: deform_k< 16,3><<<nb, 64, 0, stream>>>(cur, ws, off_b, dc_b, dc, sums); break;
    }
    se_k<<<1, 256, 0, stream>>>(sums, se_w1, se_b1, se_w2, se_b2, g, l, P);
    fuse_k<<<nb, 64, 0, stream>>>(dc, g, ws, tmp[l], l, P);
  }
  final_k<<<16384, 256, 0, stream>>>(ws, fuse_b, out);
}

// Round 4
// 306.531 us; speedup vs baseline: 6.4323x; 2.5326x over previous
//
#include <hip/hip_runtime.h>
#include <math.h>

// All reference tensors are float32 -> inputs are const float*, output float*.

constexpr int Bn = 4;          // batch

typedef __attribute__((ext_vector_type(8))) short short8;   // 8 bf16 (4 VGPRs)
typedef __attribute__((ext_vector_type(4))) float f32x4;    // MFMA 16x16 acc

static __device__ __forceinline__ short f2b(float f){
  union { float f; unsigned u; } v; v.f = f;
  unsigned r = v.u + 0x7fffu + ((v.u >> 16) & 1u);   // RNE
  return (short)(r >> 16);
}

// ---- workspace layout (float offsets; all multiples of 4 -> 16B aligned) ----
constexpr size_t OFF_CUR   = 0;                         // 4*16384*64 f32 NHWC
constexpr size_t OFF_DC    = OFF_CUR  + 4194304;        // 4*16384*64 f32 NHWC
constexpr size_t OFF_T0    = OFF_DC   + 4194304;        // fuse outputs, CHW [b][o][p]
constexpr size_t OFF_T1    = OFF_T0   + 4194304;
constexpr size_t OFF_T2    = OFF_T1   + 1048576;
constexpr size_t OFF_T3    = OFF_T2   + 262144;
constexpr size_t OFF_WSUMT = OFF_T3   + 65536;          // bf16 [4][64][64]
constexpr size_t OFF_DCWT  = OFF_WSUMT + 8192;          // bf16 [4][64][576]
constexpr size_t OFF_OWT   = OFF_DCWT  + 73728;         // bf16 [4][32][576]
constexpr size_t OFF_SUMS  = OFF_OWT   + 36864;         // f32 [4][64 slots][256]
constexpr size_t OFF_G     = OFF_SUMS  + 65536;         // f32 [4][4][64]

// ---- prep: convert weights to bf16 (N-major, K-contiguous), cumulative fuse, zero SE sums ----
__global__ void prep_k(const float* __restrict__ dc_w, const float* __restrict__ off_w,
                       const float* __restrict__ fuse_w, float* __restrict__ ws){
  int i = blockIdx.x * 256 + threadIdx.x;
  short* dcwT  = (short*)(ws + OFF_DCWT);
  short* owT   = (short*)(ws + OFF_OWT);
  short* wsumT = (short*)(ws + OFF_WSUMT);
  if (i < 147456){
    dcwT[i] = f2b(dc_w[i]);                       // [l][o][c*9+kt] == flat order
  } else if (i < 147456 + 73728){
    int t = i - 147456;
    int l = t / 18432, r = t % 18432, m = r / 576, k = r % 576;
    owT[t] = (m < 18) ? f2b(off_w[(l*18 + m)*576 + k]) : (short)0;
  } else if (i < 147456 + 73728 + 16384){
    int t = i - (147456 + 73728);
    int l = t / 4096, r = t % 4096, o = r / 64, c = r % 64;
    float s = 0.f;
    for (int jl = 0; jl <= l; jl++) s += fuse_w[o*256 + jl*64 + c];
    wsumT[t] = f2b(s);
  } else if (i < 147456 + 73728 + 16384 + 65536){
    ws[OFF_SUMS + (i - (147456 + 73728 + 16384))] = 0.f;
  }
}

// ---- convert x: NCHW -> NHWC via LDS-tiled transpose (coalesced both sides) ----
__global__ __launch_bounds__(256) void cvt_k(const float* __restrict__ x, float* __restrict__ cur){
  __shared__ float t[64][65];
  int tile = blockIdx.x;                 // 1024 tiles: b(4) x 256 pixel-groups
  int b = tile >> 8, p0 = (tile & 255) << 6;
  int tx = threadIdx.x & 63, ty = threadIdx.x >> 6;
  #pragma unroll
  for (int c = ty; c < 64; c += 4)
    t[c][tx] = x[(((size_t)(b << 6) + c) << 14) + p0 + tx];
  __syncthreads();
  #pragma unroll
  for (int pp = ty; pp < 64; pp += 4)
    cur[(((size_t)(b << 14)) + p0 + pp) * 64 + tx] = t[tx][pp];
}

// ---- downsample-by-2 (== 2x2 avg pool) with SE gate of previous level ----
template<int H>
__global__ void down_k(const float* __restrict__ dcin, const float* __restrict__ g,
                       float* __restrict__ cur, int lprev){
  constexpr int W = H, P = H * W;
  int i = blockIdx.x * 256 + threadIdx.x;
  if (i >= Bn * P * 64) return;
  int c = i & 63, bp = i >> 6, b = bp / P, p = bp % P, h = p / W, w = p % W;
  const int W2 = 2 * W;
  const float* s = dcin + (size_t)b * 4 * P * 64;
  size_t o00 = ((size_t)(2*h) * W2 + 2*w) * 64 + c;
  float v = 0.25f * (s[o00] + s[o00 + 64] + s[o00 + (size_t)W2*64] + s[o00 + (size_t)W2*64 + 64]);
  cur[i] = v * g[lprev * 256 + (b << 6) + c];
}

// ---- fused: offset conv (MFMA) + bilinear sampling + deform GEMM (MFMA) + SE colsum ----
// 4 waves per block, 16 pixels per block; waves split pixels (staging) and N (GEMM)
template<int H, int LVL>
__global__ __launch_bounds__(256, 6) void deform_k(
    const float* __restrict__ cur, const float* __restrict__ ws_all,
    const float* __restrict__ off_bias, const float* __restrict__ dc_bias,
    float* __restrict__ dc, float* __restrict__ sums){
  constexpr int W = H, P = H * W;
  __shared__ __align__(16) short valA[16][584];   // bf16, pad 576->584
  __shared__ float offs[16][18];
  __shared__ int2   tapA[144];                    // {clamped idx, fp mask bits}
  __shared__ float4 tapW[144];                    // bilinear corner weights
  __shared__ int4   tapI[144];                    // clamped corner indices
  const short* owt = (const short*)(ws_all + OFF_OWT) + LVL * 32 * 576;
  const short* dcw = (const short*)(ws_all + OFF_DCWT) + (size_t)LVL * 64 * 576;
  const int tid = threadIdx.x;
  const int wave = tid >> 6, lane = tid & 63;
  const int c0 = lane & 15, quad = lane >> 4, q4 = quad * 4;
  const int pix0 = blockIdx.x * 16;
  const int b = pix0 / P, pb = pix0 % P;
  const float* curb = cur + (size_t)b * P * 64;

  // A0: per-tap patch index/mask (wave-uniform math done once, spread over threads)
  if (tid < 144){
    int p = tid / 9, k = tid % 9;
    int pp = pb + p, h = pp / W, w = pp % W;
    int yy = h + k/3 - 1, xx = w + k%3 - 1;
    bool valid = (yy >= 0) & (yy < H) & (xx >= 0) & (xx < W);
    tapA[tid] = make_int2(valid ? (yy * W + xx) : 0, valid ? __float_as_int(1.f) : 0);
  }
  __syncthreads();

  // A1: stage zero-padded patches, bf16 (lane = channel; wave's 4 pixels)
  for (int p = wave*4; p < wave*4 + 4; p++){
    #pragma unroll
    for (int k = 0; k < 9; k++){
      int2 ta = tapA[p*9 + k];
      float v = curb[(size_t)ta.x * 64 + lane] * __int_as_float(ta.y);
      valA[p][lane*9 + k] = f2b(v);
    }
  }
  __syncthreads();

  // B: offset conv via MFMA [16 x 576]@[576 x 32]; waves 0/1 take cols 16w..16w+15
  if (wave < 2){
    f32x4 oacc = {0,0,0,0};
    #pragma unroll
    for (int ch = 0; ch < 18; ch++){
      short8 a  = *(const short8*)&valA[c0][ch*32 + quad*8];
      short8 bf = *(const short8*)&owt[(wave*16 + c0)*576 + ch*32 + quad*8];
      oacc = __builtin_amdgcn_mfma_f32_16x16x32_bf16(a, bf, oacc, 0, 0, 0);
    }
    int comp = wave*16 + c0;
    if (comp < 18){
      float ob = off_bias[LVL*18 + comp];
      #pragma unroll
      for (int r = 0; r < 4; r++) offs[q4 + r][comp] = oacc[r] + ob;
    }
  }
  __syncthreads();

  // C0: per-tap bilinear weights + clamped corner indices (uniform math, once)
  if (tid < 144){
    int p = tid / 9, k = tid % 9;
    int pp = pb + p, h = pp / W, w = pp % W;
    float py = (float)(h + k/3 - 1) + offs[p][2*k];
    float px = (float)(w + k%3 - 1) + offs[p][2*k + 1];
    float y0f = floorf(py), x0f = floorf(px);
    float fy = py - y0f, fx = px - x0f;
    int y0 = (int)y0f, x0 = (int)x0f, y1 = y0 + 1, x1 = x0 + 1;
    bool vy0 = (y0 >= 0) & (y0 < H), vy1 = (y1 >= 0) & (y1 < H);
    bool vx0 = (x0 >= 0) & (x0 < W), vx1 = (x1 >= 0) & (x1 < W);
    int y0c = min(max(y0, 0), H-1), y1c = min(max(y1, 0), H-1);
    int x0c = min(max(x0, 0), W-1), x1c = min(max(x1, 0), W-1);
    float gy = 1.f - fy, gx = 1.f - fx;
    tapW[tid] = make_float4((vy0 & vx0) ? gy*gx : 0.f,
                            (vy0 & vx1) ? gy*fx : 0.f,
                            (vy1 & vx0) ? fy*gx : 0.f,
                            (vy1 & vx1) ? fy*fx : 0.f);
    tapI[tid] = make_int4(y0c*W + x0c, y0c*W + x1c, y1c*W + x0c, y1c*W + x1c);
  }
  __syncthreads();

  // C1: sample (lane = channel; wave's 4 pixels); overwrite valA
  for (int p = wave*4; p < wave*4 + 4; p++){
    #pragma unroll
    for (int k = 0; k < 9; k++){
      float4 wv = tapW[p*9 + k];
      int4   iv = tapI[p*9 + k];
      float v = wv.x * curb[(size_t)iv.x*64 + lane]
              + wv.y * curb[(size_t)iv.y*64 + lane]
              + wv.z * curb[(size_t)iv.z*64 + lane]
              + wv.w * curb[(size_t)iv.w*64 + lane];
      valA[p][lane*9 + k] = f2b(v);
    }
  }
  __syncthreads();

  // D: deform GEMM [16 x 576]@[576 x 64]; wave w takes cols 16w..16w+15
  const int n = wave*16 + c0;
  float bt = dc_bias[LVL*64 + n];
  f32x4 acc = {bt, bt, bt, bt};
  #pragma unroll
  for (int ch = 0; ch < 18; ch++){
    short8 a  = *(const short8*)&valA[c0][ch*32 + quad*8];
    short8 bf = *(const short8*)&dcw[n*576 + ch*32 + quad*8];
    acc = __builtin_amdgcn_mfma_f32_16x16x32_bf16(a, bf, acc, 0, 0, 0);
  }
  float* dcb = dc + (size_t)pix0 * 64;
  #pragma unroll
  for (int r = 0; r < 4; r++) dcb[(q4 + r)*64 + n] = acc[r];
  float s = acc[0] + acc[1] + acc[2] + acc[3];
  s += __shfl_xor(s, 16);
  s += __shfl_xor(s, 32);
  if (quad == 0) atomicAdd(&sums[(LVL*64 + (blockIdx.x & 63))*256 + (b << 6) + n], s);
}

// ---- SE: reduce slotted sums -> mean -> fc-relu-fc-sigmoid -> gates ----
__global__ void se_k(const float* __restrict__ sums, const float* __restrict__ w1p,
                     const float* __restrict__ b1p, const float* __restrict__ w2p,
                     const float* __restrict__ b2p, float* __restrict__ g, int l, int P){
  __shared__ float m_s[256];
  __shared__ float h_s[16];
  int t = threadIdx.x;
  float s = 0.f;
  for (int slot = 0; slot < 64; slot++) s += sums[(l*64 + slot)*256 + t];
  m_s[t] = s / (float)P;
  __syncthreads();
  if (t < 16){
    int b = t >> 2, r = t & 3;
    float a = b1p[l*4 + r];
    for (int c = 0; c < 64; c++) a += m_s[b*64 + c] * w1p[(l*4 + r)*64 + c];
    h_s[t] = fmaxf(a, 0.f);
  }
  __syncthreads();
  int b = t >> 6, c = t & 63;
  float a = b2p[l*64 + c];
  for (int r = 0; r < 4; r++) a += h_s[b*4 + r] * w2p[(l*64 + c)*4 + r];
  g[l*256 + t] = 1.f / (1.f + expf(-a));
}

// ---- fuse: per-pixel (dc * gate) @ Wsum_l via MFMA -> tmp_l (CHW, float4 stores) ----
__global__ __launch_bounds__(256) void fuse_k(const float* __restrict__ dcv, const float* __restrict__ g,
                                              const float* __restrict__ ws_all, float* __restrict__ tmp,
                                              int l, int P){
  __shared__ __align__(16) short fA[4][16][72];   // per-wave tile, pad 64->72
  const short* wsl = (const short*)(ws_all + OFF_WSUMT) + l * 4096;
  const int tid = threadIdx.x, wave = tid >> 6, lane = tid & 63;
  const int c0 = lane & 15, quad = lane >> 4, q4 = quad * 4;
  const int pix0 = blockIdx.x * 64 + wave * 16;
  const int b = pix0 / P, pl = pix0 - b * P;
  float gl = g[l*256 + (b << 6) + lane];
  for (int p = 0; p < 16; p++)
    fA[wave][p][lane] = f2b(dcv[(size_t)(pix0 + p)*64 + lane] * gl);
  __syncthreads();
  f32x4 acc[4] = {{0,0,0,0},{0,0,0,0},{0,0,0,0},{0,0,0,0}};
  #pragma unroll
  for (int ch = 0; ch < 2; ch++){
    short8 a = *(const short8*)&fA[wave][c0][ch*32 + quad*8];
    #pragma unroll
    for (int t = 0; t < 4; t++){
      short8 bf = *(const short8*)&wsl[(t*16 + c0)*64 + ch*32 + quad*8];
      acc[t] = __builtin_amdgcn_mfma_f32_16x16x32_bf16(a, bf, acc[t], 0, 0, 0);
    }
  }
  #pragma unroll
  for (int t = 0; t < 4; t++){
    int n = t*16 + c0;
    *(f32x4*)&tmp[(size_t)((b << 6) + n) * P + pl + q4] = acc[t];
  }
}

// ---- final: 4x bilinear upsample (CHW planes) + sum + fuse bias -> f32 NCHW ----
__global__ void final_k(const float* __restrict__ ws_all, const float* __restrict__ fuse_bias,
                        float* __restrict__ out){
  int i = blockIdx.x * 256 + threadIdx.x;
  int w = i & 127, h = (i >> 7) & 127, o = (i >> 14) & 63, b = i >> 20;
  float acc = fuse_bias[o] + ws_all[OFF_T0 + (((size_t)(b << 6) + o) << 14) + (h << 7) + w];
  const float* tarr[3] = {ws_all + OFF_T1, ws_all + OFF_T2, ws_all + OFF_T3};
  #pragma unroll
  for (int li = 0; li < 3; li++){
    int l = li + 1, Hl = 128 >> l;
    float scale = 1.0f / (float)(1 << l);
    float sy = fminf(fmaxf((h + 0.5f)*scale - 0.5f, 0.f), (float)(Hl - 1));
    float sx = fminf(fmaxf((w + 0.5f)*scale - 0.5f, 0.f), (float)(Hl - 1));
    int y0 = (int)sy, x0 = (int)sx;
    float fy = sy - y0, fx = sx - x0;
    int y1 = min(y0 + 1, Hl - 1), x1 = min(x0 + 1, Hl - 1);
    const float* tb = tarr[li] + (size_t)((b << 6) + o) * Hl * Hl;
    float v00 = tb[y0*Hl + x0], v01 = tb[y0*Hl + x1];
    float v10 = tb[y1*Hl + x0], v11 = tb[y1*Hl + x1];
    acc += (1.f-fy)*((1.f-fx)*v00 + fx*v01) + fy*((1.f-fx)*v10 + fx*v11);
  }
  out[i] = acc;
}

extern "C" void kernel_launch(void* const* d_in, const int* in_sizes, int n_in,
                              void* d_out, int out_size, void* d_ws, size_t ws_size,
                              hipStream_t stream){
  (void)in_sizes; (void)n_in; (void)out_size; (void)ws_size;
  const float* x      = (const float*)d_in[0];
  const float* off_w  = (const float*)d_in[1];
  const float* off_b  = (const float*)d_in[2];
  const float* dc_w   = (const float*)d_in[3];
  const float* dc_b   = (const float*)d_in[4];
  const float* se_w1  = (const float*)d_in[5];
  const float* se_b1  = (const float*)d_in[6];
  const float* se_w2  = (const float*)d_in[7];
  const float* se_b2  = (const float*)d_in[8];
  const float* fuse_w = (const float*)d_in[9];
  const float* fuse_b = (const float*)d_in[10];
  float* out = (float*)d_out;
  float* ws = (float*)d_ws;
  float* cur  = ws + OFF_CUR;
  float* dc   = ws + OFF_DC;
  float* tmp[4] = {ws + OFF_T0, ws + OFF_T1, ws + OFF_T2, ws + OFF_T3};
  float* sums = ws + OFF_SUMS;
  float* g    = ws + OFF_G;

  prep_k<<<(303104 + 255)/256, 256, 0, stream>>>(dc_w, off_w, fuse_w, ws);
  cvt_k<<<1024, 256, 0, stream>>>(x, cur);

  for (int l = 0; l < 4; l++){
    int H = 128 >> l, P = H * H;
    if (l > 0){
      int N = Bn * P * 64;
      int nb = (N + 255) / 256;
      if      (H == 64) down_k<64><<<nb, 256, 0, stream>>>(dc, g, cur, l - 1);
      else if (H == 32) down_k<32><<<nb, 256, 0, stream>>>(dc, g, cur, l - 1);
      else              down_k<16><<<nb, 256, 0, stream>>>(dc, g, cur, l - 1);
    }
    int nb = Bn * P / 16;
    switch (l){
      case 0: deform_k<128,0><<<nb, 256, 0, stream>>>(cur, ws, off_b, dc_b, dc, sums); break;
      case 1: deform_k< 64,1><<<nb, 256, 0, stream>>>(cur, ws, off_b, dc_b, dc, sums); break;
      case 2: deform_k< 32,2><<<nb, 256, 0, stream>>>(cur, ws, off_b, dc_b, dc, sums); break;
      case 3: deform_k< 16,3><<<nb, 256, 0, stream>>>(cur, ws, off_b, dc_b, dc, sums); break;
    }
    se_k<<<1, 256, 0, stream>>>(sums, se_w1, se_b1, se_w2, se_b2, g, l, P);
    fuse_k<<<Bn * P / 64, 256, 0, stream>>>(dc, g, ws, tmp[l], l, P);
  }
  final_k<<<16384, 256, 0, stream>>>(ws, fuse_b, out);
}